// Round 1
// baseline (919.199 us; speedup 1.0000x reference)
//
#include <hip/hip_runtime.h>
#include <math.h>

#define BB   16384
#define OBS  512
#define NE   16
#define ACTD 256
#define TK   4

// ---------------- ws layout ----------------
// [0, 64)                      : int counts[16]
// [64, 64 + NE*BB*4)           : int rowlist[NE][BB]
// [64 + NE*BB*4, + NE*BB*4)    : float problist[NE][BB]
#define WS_ROWLIST_OFF 64
#define WS_PROBLIST_OFF (64 + NE * BB * 4)

// -------------------------------------------------------------------------
// Router: one wave per row (4 rows per wave, 16 rows per 256-thread block).
// router_w (16x512 fp32 = 32KB) cached in LDS. Dot via float4 + butterfly.
// -------------------------------------------------------------------------
__global__ __launch_bounds__(256) void router_kernel(
    const float* __restrict__ x, const float* __restrict__ rw,
    const float* __restrict__ rb,
    int* __restrict__ counts, int* __restrict__ rowlist,
    float* __restrict__ problist)
{
    __shared__ float wlds[NE * OBS];
    const float4* rw4 = (const float4*)rw;
    float4* wl4 = (float4*)wlds;
    for (int i = threadIdx.x; i < NE * OBS / 4; i += 256) wl4[i] = rw4[i];
    __syncthreads();

    const int wave = threadIdx.x >> 6;
    const int lane = threadIdx.x & 63;
    const int row_base = blockIdx.x * 16 + wave * 4;

    for (int rr = 0; rr < 4; ++rr) {
        const int row = row_base + rr;
        const float4* xr = (const float4*)(x + (size_t)row * OBS);
        float4 xa = xr[lane];        // covers cols [0,256)
        float4 xb = xr[64 + lane];   // covers cols [256,512)

        float p[NE];
        float m = -1e30f;
        for (int e = 0; e < NE; ++e) {
            const float4* we = (const float4*)(wlds + e * OBS);
            float4 wa = we[lane];
            float4 wb = we[64 + lane];
            float d = xa.x * wa.x + xa.y * wa.y + xa.z * wa.z + xa.w * wa.w
                    + xb.x * wb.x + xb.y * wb.y + xb.z * wb.z + xb.w * wb.w;
            #pragma unroll
            for (int off = 32; off; off >>= 1) d += __shfl_xor(d, off, 64);
            d += rb[e];
            p[e] = d;
            m = fmaxf(m, d);
        }
        float s = 0.f;
        for (int e = 0; e < NE; ++e) { p[e] = __expf(p[e] - m); s += p[e]; }
        const float inv = 1.f / s;
        for (int e = 0; e < NE; ++e) p[e] *= inv;

        // top-4, lowest-index wins ties (matches lax.top_k set semantics)
        int   sel_e[TK];
        float sel_p[TK];
        #pragma unroll
        for (int k = 0; k < TK; ++k) {
            float best = -1.f; int be = 0;
            for (int e = 0; e < NE; ++e)
                if (p[e] > best) { best = p[e]; be = e; }
            sel_e[k] = be; sel_p[k] = best; p[be] = -2.f;
        }
        if (lane < TK) {
            const int e = sel_e[lane];
            const int pos = atomicAdd(&counts[e], 1);
            rowlist[e * BB + pos]  = row;
            problist[e * BB + pos] = sel_p[lane];
        }
    }
}

// -------------------------------------------------------------------------
// Expert-grouped GEMM. grid = (512 row-tiles, 16 experts, 4)
//   z bit0: which 128-col half of ACT, z bit1: 0=mean, 1=log_std
// Tile: 32 rows x 128 cols, K-tile 32, 256 threads, 4x4 micro-tile.
// LDS tiles stored K-major so fragments read as float4.
// Epilogue: atomicAdd p*(acc+bias) into out (4 expert contributions/elem).
// -------------------------------------------------------------------------
__global__ __launch_bounds__(256) void moe_gemm(
    const float* __restrict__ x,
    const float* __restrict__ mean_w, const float* __restrict__ mean_b,
    const float* __restrict__ lstd_w, const float* __restrict__ lstd_b,
    const int* __restrict__ counts, const int* __restrict__ rowlist,
    const float* __restrict__ problist, float* __restrict__ out)
{
    const int e = blockIdx.y;
    const int cnt = counts[e];
    const int tile0 = blockIdx.x * 32;
    if (tile0 >= cnt) return;

    const int zz    = blockIdx.z;
    const int which = zz >> 1;          // 0 = mean, 1 = log_std
    const int ctile = (zz & 1) * 128;
    const float* W    = (which ? lstd_w : mean_w) + (size_t)e * ACTD * OBS;
    const float* bias = (which ? lstd_b : mean_b) + e * ACTD;
    float* outp = out + (size_t)which * BB * ACTD;

    __shared__ float xls[32][32];    // [k][row]
    __shared__ float wls[32][128];   // [k][col]

    // staging assignment (fixed per thread)
    const int sr  = threadIdx.x >> 3;   // 0..31 (row for x-stage)
    const int skq = threadIdx.x & 7;    // 0..7  (float4 chunk along K)
    int stage_row = -1;
    {
        const int pos = tile0 + sr;
        if (pos < cnt) stage_row = rowlist[e * BB + pos];
    }

    const int r0 = (threadIdx.x >> 5) << 2;   // 0,4,...,28
    const int c0 = (threadIdx.x & 31) << 2;   // 0,4,...,124

    float acc[4][4] = {};

    for (int kt = 0; kt < OBS; kt += 32) {
        __syncthreads();
        // stage x tile (transpose to [k][row])
        {
            float4 v = make_float4(0.f, 0.f, 0.f, 0.f);
            if (stage_row >= 0)
                v = *(const float4*)(x + (size_t)stage_row * OBS + kt + skq * 4);
            xls[skq * 4 + 0][sr] = v.x;
            xls[skq * 4 + 1][sr] = v.y;
            xls[skq * 4 + 2][sr] = v.z;
            xls[skq * 4 + 3][sr] = v.w;
        }
        // stage W tile (transpose to [k][col]); 1024 float4s, 4 per thread
        #pragma unroll
        for (int j = 0; j < 4; ++j) {
            const int i  = threadIdx.x + 256 * j;
            const int c  = i >> 3;
            const int kq = i & 7;
            float4 v = *(const float4*)(W + (size_t)(ctile + c) * OBS + kt + kq * 4);
            wls[kq * 4 + 0][c] = v.x;
            wls[kq * 4 + 1][c] = v.y;
            wls[kq * 4 + 2][c] = v.z;
            wls[kq * 4 + 3][c] = v.w;
        }
        __syncthreads();

        #pragma unroll
        for (int k = 0; k < 32; ++k) {
            const float4 xa = *(const float4*)&xls[k][r0];
            const float4 wb = *(const float4*)&wls[k][c0];
            const float xv[4] = { xa.x, xa.y, xa.z, xa.w };
            const float wv[4] = { wb.x, wb.y, wb.z, wb.w };
            #pragma unroll
            for (int i = 0; i < 4; ++i)
                #pragma unroll
                for (int j = 0; j < 4; ++j)
                    acc[i][j] = fmaf(xv[i], wv[j], acc[i][j]);
        }
    }

    // epilogue: p * (acc + bias) -> atomicAdd
    #pragma unroll
    for (int i = 0; i < 4; ++i) {
        const int pos = tile0 + r0 + i;
        if (pos >= cnt) break;
        const int grow = rowlist[e * BB + pos];
        const float pw = problist[e * BB + pos];
        float* orow = outp + (size_t)grow * ACTD + ctile + c0;
        #pragma unroll
        for (int j = 0; j < 4; ++j)
            atomicAdd(&orow[j], pw * (acc[i][j] + bias[ctile + c0 + j]));
    }
}

// -------------------------------------------------------------------------
// tanh + affine epilogue on the log_std half (in place).
// -------------------------------------------------------------------------
__global__ __launch_bounds__(256) void tanh_ep(float* __restrict__ out)
{
    const int i = blockIdx.x * 256 + threadIdx.x;   // over (BB*ACTD)/4 float4
    float4* p = (float4*)(out + (size_t)BB * ACTD);
    float4 v = p[i];
    v.x = -5.f + 3.5f * (tanhf(v.x) + 1.f);
    v.y = -5.f + 3.5f * (tanhf(v.y) + 1.f);
    v.z = -5.f + 3.5f * (tanhf(v.z) + 1.f);
    v.w = -5.f + 3.5f * (tanhf(v.w) + 1.f);
    p[i] = v;
}

extern "C" void kernel_launch(void* const* d_in, const int* in_sizes, int n_in,
                              void* d_out, int out_size, void* d_ws, size_t ws_size,
                              hipStream_t stream)
{
    const float* x        = (const float*)d_in[0];
    const float* router_w = (const float*)d_in[1];
    const float* router_b = (const float*)d_in[2];
    const float* mean_w   = (const float*)d_in[3];
    const float* mean_b   = (const float*)d_in[4];
    const float* lstd_w   = (const float*)d_in[5];
    const float* lstd_b   = (const float*)d_in[6];
    // d_in[7] = router_noise (0, unused)

    float* out = (float*)d_out;
    int*   counts   = (int*)d_ws;
    int*   rowlist  = (int*)((char*)d_ws + WS_ROWLIST_OFF);
    float* problist = (float*)((char*)d_ws + WS_PROBLIST_OFF);

    // zero the accumulator (d_out) and the expert counters
    hipMemsetAsync(d_out, 0, (size_t)out_size * sizeof(float), stream);
    hipMemsetAsync(d_ws, 0, 64, stream);

    router_kernel<<<BB / 16, 256, 0, stream>>>(x, router_w, router_b,
                                               counts, rowlist, problist);

    dim3 grid(BB / 32, NE, 4);
    moe_gemm<<<grid, 256, 0, stream>>>(x, mean_w, mean_b, lstd_w, lstd_b,
                                       counts, rowlist, problist, out);

    tanh_ep<<<(BB * ACTD / 4) / 256, 256, 0, stream>>>(out);
}

// Round 4
// 520.907 us; speedup vs baseline: 1.7646x; 1.7646x over previous
//
#include <hip/hip_runtime.h>
#include <math.h>

#define BB   16384
#define OBS  512
#define NE   16
#define ACTD 256
#define TK   4

// ---------------- ws layout ----------------
// Tier B (always safe, ~2.1 MB):
//   [0,64): counts[16] | [64,+1MB): rowlist[NE][BB] | [+1MB): problist[NE][BB]
// Tier A additionally (total ~27.3 MB):
//   xbf[BB][OBS] bf16 | wmean_bf | wlstd_bf
#define WS_ROWLIST_OFF  ((size_t)64)
#define WS_PROBLIST_OFF (WS_ROWLIST_OFF + (size_t)NE * BB * 4)
#define WS_XBF_OFF      (WS_PROBLIST_OFF + (size_t)NE * BB * 4)
#define WS_WM_OFF       (WS_XBF_OFF + (size_t)BB * OBS * 2)
#define WS_WL_OFF       (WS_WM_OFF + (size_t)NE * ACTD * OBS * 2)
#define WS_NEEDED_A     (WS_WL_OFF + (size_t)NE * ACTD * OBS * 2)

typedef __attribute__((ext_vector_type(8))) short short8;
typedef __attribute__((ext_vector_type(4))) float floatx4;

__device__ __forceinline__ ushort f2bf(float f) {
    union { float f; unsigned u; } v; v.f = f;
    unsigned r = v.u + 0x7fffu + ((v.u >> 16) & 1u);
    return (ushort)(r >> 16);
}

// -------------------------------------------------------------------------
// fp32 -> bf16 conversion (weights), tier A only
// -------------------------------------------------------------------------
__global__ __launch_bounds__(256) void cvt_bf16(const float* __restrict__ src,
                                                ushort* __restrict__ dst, int n4)
{
    const int i = blockIdx.x * 256 + threadIdx.x;
    if (i >= n4) return;
    float4 v = ((const float4*)src)[i];
    ushort4 o;
    o.x = f2bf(v.x); o.y = f2bf(v.y); o.z = f2bf(v.z); o.w = f2bf(v.w);
    ((ushort4*)dst)[i] = o;
}

// -------------------------------------------------------------------------
// Router: one wave per 4 rows, fp32 logits. Optionally emits bf16 x.
// -------------------------------------------------------------------------
__global__ __launch_bounds__(256) void router_kernel(
    const float* __restrict__ x, const float* __restrict__ rw,
    const float* __restrict__ rb,
    int* __restrict__ counts, int* __restrict__ rowlist,
    float* __restrict__ problist, ushort* __restrict__ xbf, int do_xbf)
{
    __shared__ float wlds[NE * OBS];
    const float4* rw4 = (const float4*)rw;
    float4* wl4 = (float4*)wlds;
    for (int i = threadIdx.x; i < NE * OBS / 4; i += 256) wl4[i] = rw4[i];
    __syncthreads();

    const int wave = threadIdx.x >> 6;
    const int lane = threadIdx.x & 63;
    const int row_base = blockIdx.x * 16 + wave * 4;

    for (int rr = 0; rr < 4; ++rr) {
        const int row = row_base + rr;
        const float4* xr = (const float4*)(x + (size_t)row * OBS);
        float4 xa = xr[lane];
        float4 xb = xr[64 + lane];

        if (do_xbf) {
            ushort4 oa, ob;
            oa.x = f2bf(xa.x); oa.y = f2bf(xa.y); oa.z = f2bf(xa.z); oa.w = f2bf(xa.w);
            ob.x = f2bf(xb.x); ob.y = f2bf(xb.y); ob.z = f2bf(xb.z); ob.w = f2bf(xb.w);
            ushort4* xo = (ushort4*)(xbf + (size_t)row * OBS);
            xo[lane] = oa;
            xo[64 + lane] = ob;
        }

        float p[NE];
        #pragma unroll
        for (int e = 0; e < NE; ++e) {
            const float4* we = (const float4*)(wlds + e * OBS);
            float4 wa = we[lane];
            float4 wb = we[64 + lane];
            p[e] = xa.x * wa.x + xa.y * wa.y + xa.z * wa.z + xa.w * wa.w
                 + xb.x * wb.x + xb.y * wb.y + xb.z * wb.z + xb.w * wb.w;
        }
        #pragma unroll
        for (int off = 32; off; off >>= 1)
            #pragma unroll
            for (int e = 0; e < NE; ++e)
                p[e] += __shfl_xor(p[e], off, 64);

        float m = -1e30f;
        #pragma unroll
        for (int e = 0; e < NE; ++e) { p[e] += rb[e]; m = fmaxf(m, p[e]); }
        float s = 0.f;
        #pragma unroll
        for (int e = 0; e < NE; ++e) { p[e] = __expf(p[e] - m); s += p[e]; }
        const float inv = 1.f / s;
        #pragma unroll
        for (int e = 0; e < NE; ++e) p[e] *= inv;

        int   sel_e[TK];
        float sel_p[TK];
        #pragma unroll
        for (int k = 0; k < TK; ++k) {
            float best = -1.f; int be = 0;
            #pragma unroll
            for (int e = 0; e < NE; ++e)
                if (p[e] > best) { best = p[e]; be = e; }
            sel_e[k] = be; sel_p[k] = best;
            #pragma unroll
            for (int e = 0; e < NE; ++e)
                if (e == be) p[e] = -2.f;
        }
        if (lane < TK) {
            const int e = sel_e[lane];
            const int pos = atomicAdd(&counts[e], 1);
            rowlist[e * BB + pos]  = row;
            problist[e * BB + pos] = sel_p[lane];
        }
    }
}

// -------------------------------------------------------------------------
// Tier A: expert-grouped bf16 MFMA GEMM. grid = (128 row-tiles, 16, 4)
// Tile 128x128, BK=64, mfma_f32_16x16x32_bf16, 4 waves (2x2 of 64x64).
// XOR-swizzled LDS (slot = chunk ^ (row&7)): conflict-free DMA + b128 reads.
// -------------------------------------------------------------------------
__global__ __launch_bounds__(256) void moe_gemm_mfma(
    const ushort* __restrict__ xbf,
    const ushort* __restrict__ wmean, const ushort* __restrict__ wlstd,
    const float* __restrict__ mean_b, const float* __restrict__ lstd_b,
    const int* __restrict__ counts, const int* __restrict__ rowlist,
    const float* __restrict__ problist, float* __restrict__ out)
{
    const int e   = blockIdx.y;
    const int cnt = counts[e];
    const int tile0 = blockIdx.x * 128;
    if (tile0 >= cnt) return;

    const int zz    = blockIdx.z;
    const int which = zz >> 1;
    const int ctile = (zz & 1) * 128;
    const ushort* W   = (which ? wlstd : wmean) + (size_t)e * ACTD * OBS;
    const float* bias = (which ? lstd_b : mean_b) + e * ACTD + ctile;
    float* outp = out + (size_t)which * BB * ACTD;

    __shared__ __align__(16) ushort xls[128 * 64];
    __shared__ __align__(16) ushort wls[128 * 64];
    __shared__ int   rows_l[128];
    __shared__ float probs_l[128];

    const int tid = threadIdx.x;
    const int l   = tid & 63;
    const int w   = tid >> 6;

    if (tid < 128) {
        const int pos = tile0 + tid;
        rows_l[tid]  = (pos < cnt) ? rowlist[e * BB + pos] : -1;
        probs_l[tid] = (pos < cnt) ? problist[e * BB + pos] : 0.f;
    }

    const int c_sw = (l & 7) ^ (l >> 3);
    const ushort* xptr[4];
    const ushort* wptr[4];
    #pragma unroll
    for (int i = 0; i < 4; ++i) {
        const int lrow = 32 * w + 8 * i + (l >> 3);
        const int pos  = tile0 + lrow;
        const int grow = (pos < cnt) ? rowlist[e * BB + pos] : rowlist[e * BB + tile0];
        xptr[i] = xbf + (size_t)grow * OBS + c_sw * 8;
        wptr[i] = W + (size_t)(ctile + lrow) * OBS + c_sw * 8;
    }

    const int wm  = (w >> 1) * 64;
    const int wn  = (w & 1) * 64;
    const int rlo = l & 15;
    const int q   = l >> 4;
    const int r7  = rlo & 7;

    floatx4 acc[4][4];
    #pragma unroll
    for (int mi = 0; mi < 4; ++mi)
        #pragma unroll
        for (int ni = 0; ni < 4; ++ni)
            acc[mi][ni] = (floatx4){0.f, 0.f, 0.f, 0.f};

    for (int kt = 0; kt < OBS; kt += 64) {
        __syncthreads();
        #pragma unroll
        for (int i = 0; i < 4; ++i) {
            __builtin_amdgcn_global_load_lds(
                (const __attribute__((address_space(1))) unsigned int*)(xptr[i] + kt),
                (__attribute__((address_space(3))) unsigned int*)(xls + (4 * w + i) * 512),
                16, 0, 0);
            __builtin_amdgcn_global_load_lds(
                (const __attribute__((address_space(1))) unsigned int*)(wptr[i] + kt),
                (__attribute__((address_space(3))) unsigned int*)(wls + (4 * w + i) * 512),
                16, 0, 0);
        }
        __syncthreads();

        #pragma unroll
        for (int ks = 0; ks < 2; ++ks) {
            short8 af[4], bfr[4];
            #pragma unroll
            for (int mi = 0; mi < 4; ++mi) {
                const int row = wm + mi * 16 + rlo;
                const int ch  = (4 * ks + q) ^ r7;
                af[mi] = *(const short8*)(xls + row * 64 + ch * 8);
            }
            #pragma unroll
            for (int ni = 0; ni < 4; ++ni) {
                const int row = wn + ni * 16 + rlo;
                const int ch  = (4 * ks + q) ^ r7;
                bfr[ni] = *(const short8*)(wls + row * 64 + ch * 8);
            }
            #pragma unroll
            for (int mi = 0; mi < 4; ++mi)
                #pragma unroll
                for (int ni = 0; ni < 4; ++ni)
                    acc[mi][ni] = __builtin_amdgcn_mfma_f32_16x16x32_bf16(
                        af[mi], bfr[ni], acc[mi][ni], 0, 0, 0);
        }
    }

    #pragma unroll
    for (int mi = 0; mi < 4; ++mi) {
        #pragma unroll
        for (int r = 0; r < 4; ++r) {
            const int lrow = wm + mi * 16 + q * 4 + r;
            const int grow = rows_l[lrow];
            if (grow < 0) continue;
            const float pw = probs_l[lrow];
            float* orow = outp + (size_t)grow * ACTD + ctile + wn + rlo;
            #pragma unroll
            for (int ni = 0; ni < 4; ++ni)
                atomicAdd(orow + ni * 16,
                          pw * (acc[mi][ni][r] + bias[wn + ni * 16 + rlo]));
        }
    }
}

// -------------------------------------------------------------------------
// Tier B: fp32 expert-grouped GEMM (round-1, proven). grid = (512, 16, 4)
// -------------------------------------------------------------------------
__global__ __launch_bounds__(256) void moe_gemm_f32(
    const float* __restrict__ x,
    const float* __restrict__ mean_w, const float* __restrict__ mean_b,
    const float* __restrict__ lstd_w, const float* __restrict__ lstd_b,
    const int* __restrict__ counts, const int* __restrict__ rowlist,
    const float* __restrict__ problist, float* __restrict__ out)
{
    const int e = blockIdx.y;
    const int cnt = counts[e];
    const int tile0 = blockIdx.x * 32;
    if (tile0 >= cnt) return;

    const int zz    = blockIdx.z;
    const int which = zz >> 1;
    const int ctile = (zz & 1) * 128;
    const float* W    = (which ? lstd_w : mean_w) + (size_t)e * ACTD * OBS;
    const float* bias = (which ? lstd_b : mean_b) + e * ACTD;
    float* outp = out + (size_t)which * BB * ACTD;

    __shared__ float xls[32][32];
    __shared__ float wls[32][128];

    const int sr  = threadIdx.x >> 3;
    const int skq = threadIdx.x & 7;
    int stage_row = -1;
    {
        const int pos = tile0 + sr;
        if (pos < cnt) stage_row = rowlist[e * BB + pos];
    }

    const int r0 = (threadIdx.x >> 5) << 2;
    const int c0 = (threadIdx.x & 31) << 2;

    float acc[4][4] = {};

    for (int kt = 0; kt < OBS; kt += 32) {
        __syncthreads();
        {
            float4 v = make_float4(0.f, 0.f, 0.f, 0.f);
            if (stage_row >= 0)
                v = *(const float4*)(x + (size_t)stage_row * OBS + kt + skq * 4);
            xls[skq * 4 + 0][sr] = v.x;
            xls[skq * 4 + 1][sr] = v.y;
            xls[skq * 4 + 2][sr] = v.z;
            xls[skq * 4 + 3][sr] = v.w;
        }
        #pragma unroll
        for (int j = 0; j < 4; ++j) {
            const int i  = threadIdx.x + 256 * j;
            const int c  = i >> 3;
            const int kq = i & 7;
            float4 v = *(const float4*)(W + (size_t)(ctile + c) * OBS + kt + kq * 4);
            wls[kq * 4 + 0][c] = v.x;
            wls[kq * 4 + 1][c] = v.y;
            wls[kq * 4 + 2][c] = v.z;
            wls[kq * 4 + 3][c] = v.w;
        }
        __syncthreads();

        #pragma unroll
        for (int k = 0; k < 32; ++k) {
            const float4 xa = *(const float4*)&xls[k][r0];
            const float4 wb = *(const float4*)&wls[k][c0];
            const float xv[4] = { xa.x, xa.y, xa.z, xa.w };
            const float wv[4] = { wb.x, wb.y, wb.z, wb.w };
            #pragma unroll
            for (int i = 0; i < 4; ++i)
                #pragma unroll
                for (int j = 0; j < 4; ++j)
                    acc[i][j] = fmaf(xv[i], wv[j], acc[i][j]);
        }
    }

    #pragma unroll
    for (int i = 0; i < 4; ++i) {
        const int pos = tile0 + r0 + i;
        if (pos >= cnt) break;
        const int grow = rowlist[e * BB + pos];
        const float pw = problist[e * BB + pos];
        float* orow = outp + (size_t)grow * ACTD + ctile + c0;
        #pragma unroll
        for (int j = 0; j < 4; ++j)
            atomicAdd(&orow[j], pw * (acc[i][j] + bias[ctile + c0 + j]));
    }
}

// -------------------------------------------------------------------------
// tanh + affine epilogue on the log_std half (in place).
// -------------------------------------------------------------------------
__global__ __launch_bounds__(256) void tanh_ep(float* __restrict__ out)
{
    const int i = blockIdx.x * 256 + threadIdx.x;
    float4* p = (float4*)(out + (size_t)BB * ACTD);
    float4 v = p[i];
    v.x = -5.f + 3.5f * (tanhf(v.x) + 1.f);
    v.y = -5.f + 3.5f * (tanhf(v.y) + 1.f);
    v.z = -5.f + 3.5f * (tanhf(v.z) + 1.f);
    v.w = -5.f + 3.5f * (tanhf(v.w) + 1.f);
    p[i] = v;
}

extern "C" void kernel_launch(void* const* d_in, const int* in_sizes, int n_in,
                              void* d_out, int out_size, void* d_ws, size_t ws_size,
                              hipStream_t stream)
{
    const float* x        = (const float*)d_in[0];
    const float* router_w = (const float*)d_in[1];
    const float* router_b = (const float*)d_in[2];
    const float* mean_w   = (const float*)d_in[3];
    const float* mean_b   = (const float*)d_in[4];
    const float* lstd_w   = (const float*)d_in[5];
    const float* lstd_b   = (const float*)d_in[6];

    float* out = (float*)d_out;
    int*    counts   = (int*)d_ws;
    int*    rowlist  = (int*)((char*)d_ws + WS_ROWLIST_OFF);
    float*  problist = (float*)((char*)d_ws + WS_PROBLIST_OFF);
    ushort* xbf      = (ushort*)((char*)d_ws + WS_XBF_OFF);
    ushort* wmbf     = (ushort*)((char*)d_ws + WS_WM_OFF);
    ushort* wlbf     = (ushort*)((char*)d_ws + WS_WL_OFF);

    const bool tierA = (ws_size >= WS_NEEDED_A);

    hipMemsetAsync(d_out, 0, (size_t)out_size * sizeof(float), stream);
    hipMemsetAsync(d_ws, 0, 64, stream);

    if (tierA) {
        const int wn4 = NE * ACTD * OBS / 4;
        cvt_bf16<<<(wn4 + 255) / 256, 256, 0, stream>>>(mean_w, wmbf, wn4);
        cvt_bf16<<<(wn4 + 255) / 256, 256, 0, stream>>>(lstd_w, wlbf, wn4);

        router_kernel<<<BB / 16, 256, 0, stream>>>(x, router_w, router_b,
                                                   counts, rowlist, problist,
                                                   xbf, 1);

        dim3 grid(BB / 128, NE, 4);
        moe_gemm_mfma<<<grid, 256, 0, stream>>>(xbf, wmbf, wlbf, mean_b, lstd_b,
                                                counts, rowlist, problist, out);
    } else {
        router_kernel<<<BB / 16, 256, 0, stream>>>(x, router_w, router_b,
                                                   counts, rowlist, problist,
                                                   (ushort*)nullptr, 0);

        dim3 grid(BB / 32, NE, 4);
        moe_gemm_f32<<<grid, 256, 0, stream>>>(x, mean_w, mean_b, lstd_w, lstd_b,
                                               counts, rowlist, problist, out);
    }

    tanh_ep<<<(BB * ACTD / 4) / 256, 256, 0, stream>>>(out);
}

// Round 5
// 257.313 us; speedup vs baseline: 3.5723x; 2.0244x over previous
//
#include <hip/hip_runtime.h>
#include <math.h>

#define BB   16384
#define OBS  512
#define NE   16
#define ACTD 256
#define TK   4

// ---------------- ws layout ----------------
// counts[16]            @ 0       (64 B)
// rowlist[NE][BB] int   @ 64      (1 MB)
// problist[NE][BB] f32  @ +1MB    (1 MB)
// slot_of[NE][BB] int   @ +2MB    (1 MB)
// xbf[BB][OBS] bf16     @ +3MB    (16 MB)
// wmean_bf              @ +19MB   (4 MB)
// wlstd_bf              @ +23MB   (4 MB)
// partial[2][BB*4][ACTD] bf16 @ +27MB (64 MB)   -- tier A2 only
#define WS_ROWLIST_OFF  ((size_t)64)
#define WS_PROBLIST_OFF (WS_ROWLIST_OFF + (size_t)NE * BB * 4)
#define WS_SLOT_OFF     (WS_PROBLIST_OFF + (size_t)NE * BB * 4)
#define WS_XBF_OFF      (WS_SLOT_OFF + (size_t)NE * BB * 4)
#define WS_WM_OFF       (WS_XBF_OFF + (size_t)BB * OBS * 2)
#define WS_WL_OFF       (WS_WM_OFF + (size_t)NE * ACTD * OBS * 2)
#define WS_PART_OFF     (WS_WL_OFF + (size_t)NE * ACTD * OBS * 2)
#define WS_NEEDED_A     (WS_PART_OFF)
#define WS_NEEDED_A2    (WS_PART_OFF + (size_t)2 * BB * TK * ACTD * 2)

typedef __attribute__((ext_vector_type(8))) short short8;
typedef __attribute__((ext_vector_type(4))) float floatx4;

__device__ __forceinline__ ushort f2bf(float f) {
    union { float f; unsigned u; } v; v.f = f;
    unsigned r = v.u + 0x7fffu + ((v.u >> 16) & 1u);
    return (ushort)(r >> 16);
}
__device__ __forceinline__ float bf2f(ushort u) {
    union { unsigned u; float f; } v; v.u = ((unsigned)u) << 16;
    return v.f;
}

// -------------------------------------------------------------------------
// fp32 -> bf16 conversion (weights)
// -------------------------------------------------------------------------
__global__ __launch_bounds__(256) void cvt_bf16(const float* __restrict__ src,
                                                ushort* __restrict__ dst, int n4)
{
    const int i = blockIdx.x * 256 + threadIdx.x;
    if (i >= n4) return;
    float4 v = ((const float4*)src)[i];
    ushort4 o;
    o.x = f2bf(v.x); o.y = f2bf(v.y); o.z = f2bf(v.z); o.w = f2bf(v.w);
    ((ushort4*)dst)[i] = o;
}

// -------------------------------------------------------------------------
// Router: 16 rows/block. Block-local LDS count aggregation -> 16 global
// RMWs per block (was 256). Emits rowlist/problist/slot_of (+ bf16 x).
// -------------------------------------------------------------------------
__global__ __launch_bounds__(256) void router_kernel(
    const float* __restrict__ x, const float* __restrict__ rw,
    const float* __restrict__ rb,
    int* __restrict__ counts, int* __restrict__ rowlist,
    float* __restrict__ problist, int* __restrict__ slot_of,
    ushort* __restrict__ xbf, int do_aux)
{
    __shared__ float wlds[NE * OBS];
    __shared__ int   lcnt[NE], lbase[NE];
    __shared__ int   s_e[64], s_lpos[64];
    __shared__ float s_p[64];

    const float4* rw4 = (const float4*)rw;
    float4* wl4 = (float4*)wlds;
    for (int i = threadIdx.x; i < NE * OBS / 4; i += 256) wl4[i] = rw4[i];
    if (threadIdx.x < NE) lcnt[threadIdx.x] = 0;
    __syncthreads();

    const int wave = threadIdx.x >> 6;
    const int lane = threadIdx.x & 63;
    const int row_base = blockIdx.x * 16 + wave * 4;

    for (int rr = 0; rr < 4; ++rr) {
        const int row = row_base + rr;
        const float4* xr = (const float4*)(x + (size_t)row * OBS);
        float4 xa = xr[lane];
        float4 xb = xr[64 + lane];

        if (do_aux) {
            ushort4 oa, ob;
            oa.x = f2bf(xa.x); oa.y = f2bf(xa.y); oa.z = f2bf(xa.z); oa.w = f2bf(xa.w);
            ob.x = f2bf(xb.x); ob.y = f2bf(xb.y); ob.z = f2bf(xb.z); ob.w = f2bf(xb.w);
            ushort4* xo = (ushort4*)(xbf + (size_t)row * OBS);
            xo[lane] = oa;
            xo[64 + lane] = ob;
        }

        float p[NE];
        #pragma unroll
        for (int e = 0; e < NE; ++e) {
            const float4* we = (const float4*)(wlds + e * OBS);
            float4 wa = we[lane];
            float4 wb = we[64 + lane];
            p[e] = xa.x * wa.x + xa.y * wa.y + xa.z * wa.z + xa.w * wa.w
                 + xb.x * wb.x + xb.y * wb.y + xb.z * wb.z + xb.w * wb.w;
        }
        #pragma unroll
        for (int off = 32; off; off >>= 1)
            #pragma unroll
            for (int e = 0; e < NE; ++e)
                p[e] += __shfl_xor(p[e], off, 64);

        float m = -1e30f;
        #pragma unroll
        for (int e = 0; e < NE; ++e) { p[e] += rb[e]; m = fmaxf(m, p[e]); }
        float s = 0.f;
        #pragma unroll
        for (int e = 0; e < NE; ++e) { p[e] = __expf(p[e] - m); s += p[e]; }
        const float inv = 1.f / s;
        #pragma unroll
        for (int e = 0; e < NE; ++e) p[e] *= inv;

        int   sel_e[TK];
        float sel_p[TK];
        #pragma unroll
        for (int k = 0; k < TK; ++k) {
            float best = -1.f; int be = 0;
            #pragma unroll
            for (int e = 0; e < NE; ++e)
                if (p[e] > best) { best = p[e]; be = e; }
            sel_e[k] = be; sel_p[k] = best;
            #pragma unroll
            for (int e = 0; e < NE; ++e)
                if (e == be) p[e] = -2.f;
        }
        if (lane < TK) {
            const int e = sel_e[lane];
            const int lpos = atomicAdd(&lcnt[e], 1);   // LDS atomic (cheap)
            const int sid = (wave * 4 + rr) * 4 + lane;
            s_e[sid] = e; s_p[sid] = sel_p[lane]; s_lpos[sid] = lpos;
        }
    }
    __syncthreads();
    if (threadIdx.x < NE)
        lbase[threadIdx.x] = atomicAdd(&counts[threadIdx.x], lcnt[threadIdx.x]);
    __syncthreads();
    if (threadIdx.x < 64) {
        const int sid = threadIdx.x;
        const int e   = s_e[sid];
        const int pos = lbase[e] + s_lpos[sid];
        const int row = blockIdx.x * 16 + (sid >> 2);
        rowlist[e * BB + pos]  = row;
        problist[e * BB + pos] = s_p[sid];
        if (do_aux) slot_of[e * BB + pos] = row * TK + (sid & 3);
    }
}

// -------------------------------------------------------------------------
// Expert-grouped bf16 MFMA GEMM. grid = (128 row-tiles, 16, 4)
// Tile 128x128, BK=64, mfma_f32_16x16x32_bf16, 4 waves (2x2 of 64x64).
// mode 1: non-atomic bf16 partial stores (slot-indexed).  mode 0: atomicAdd.
// -------------------------------------------------------------------------
__global__ __launch_bounds__(256) void moe_gemm_mfma(
    const ushort* __restrict__ xbf,
    const ushort* __restrict__ wmean, const ushort* __restrict__ wlstd,
    const float* __restrict__ mean_b, const float* __restrict__ lstd_b,
    const int* __restrict__ counts, const int* __restrict__ rowlist,
    const float* __restrict__ problist, const int* __restrict__ slot_of,
    ushort* __restrict__ partial, float* __restrict__ out, int mode)
{
    const int e   = blockIdx.y;
    const int cnt = counts[e];
    const int tile0 = blockIdx.x * 128;
    if (tile0 >= cnt) return;

    const int zz    = blockIdx.z;
    const int which = zz >> 1;
    const int ctile = (zz & 1) * 128;
    const ushort* W   = (which ? wlstd : wmean) + (size_t)e * ACTD * OBS;
    const float* bias = (which ? lstd_b : mean_b) + e * ACTD + ctile;

    __shared__ __align__(16) ushort xls[128 * 64];
    __shared__ __align__(16) ushort wls[128 * 64];
    __shared__ int   idx_l[128];     // mode1: slot, mode0: row
    __shared__ float probs_l[128];

    const int tid = threadIdx.x;
    const int l   = tid & 63;
    const int w   = tid >> 6;

    if (tid < 128) {
        const int pos = tile0 + tid;
        const bool v = pos < cnt;
        probs_l[tid] = v ? problist[e * BB + pos] : 0.f;
        idx_l[tid] = v ? (mode ? slot_of[e * BB + pos] : rowlist[e * BB + pos]) : -1;
    }

    const int c_sw = (l & 7) ^ (l >> 3);
    const ushort* xptr[4];
    const ushort* wptr[4];
    #pragma unroll
    for (int i = 0; i < 4; ++i) {
        const int lrow = 32 * w + 8 * i + (l >> 3);
        const int pos  = tile0 + lrow;
        const int grow = (pos < cnt) ? rowlist[e * BB + pos] : rowlist[e * BB + tile0];
        xptr[i] = xbf + (size_t)grow * OBS + c_sw * 8;
        wptr[i] = W + (size_t)(ctile + lrow) * OBS + c_sw * 8;
    }

    const int wm  = (w >> 1) * 64;
    const int wn  = (w & 1) * 64;
    const int rlo = l & 15;
    const int q   = l >> 4;
    const int r7  = rlo & 7;

    floatx4 acc[4][4];
    #pragma unroll
    for (int mi = 0; mi < 4; ++mi)
        #pragma unroll
        for (int ni = 0; ni < 4; ++ni)
            acc[mi][ni] = (floatx4){0.f, 0.f, 0.f, 0.f};

    for (int kt = 0; kt < OBS; kt += 64) {
        __syncthreads();
        #pragma unroll
        for (int i = 0; i < 4; ++i) {
            __builtin_amdgcn_global_load_lds(
                (const __attribute__((address_space(1))) unsigned int*)(xptr[i] + kt),
                (__attribute__((address_space(3))) unsigned int*)(xls + (4 * w + i) * 512),
                16, 0, 0);
            __builtin_amdgcn_global_load_lds(
                (const __attribute__((address_space(1))) unsigned int*)(wptr[i] + kt),
                (__attribute__((address_space(3))) unsigned int*)(wls + (4 * w + i) * 512),
                16, 0, 0);
        }
        __syncthreads();

        #pragma unroll
        for (int ks = 0; ks < 2; ++ks) {
            short8 af[4], bfr[4];
            #pragma unroll
            for (int mi = 0; mi < 4; ++mi) {
                const int row = wm + mi * 16 + rlo;
                const int ch  = (4 * ks + q) ^ r7;
                af[mi] = *(const short8*)(xls + row * 64 + ch * 8);
            }
            #pragma unroll
            for (int ni = 0; ni < 4; ++ni) {
                const int row = wn + ni * 16 + rlo;
                const int ch  = (4 * ks + q) ^ r7;
                bfr[ni] = *(const short8*)(wls + row * 64 + ch * 8);
            }
            #pragma unroll
            for (int mi = 0; mi < 4; ++mi)
                #pragma unroll
                for (int ni = 0; ni < 4; ++ni)
                    acc[mi][ni] = __builtin_amdgcn_mfma_f32_16x16x32_bf16(
                        af[mi], bfr[ni], acc[mi][ni], 0, 0, 0);
        }
    }

    if (mode) {
        // non-atomic bf16 partial stores: each slot written exactly once
        ushort* Pp = partial + (size_t)which * BB * TK * ACTD;
        #pragma unroll
        for (int mi = 0; mi < 4; ++mi) {
            #pragma unroll
            for (int r = 0; r < 4; ++r) {
                const int lrow = wm + mi * 16 + q * 4 + r;
                const int slot = idx_l[lrow];
                if (slot < 0) continue;
                const float pw = probs_l[lrow];
                ushort* orow = Pp + (size_t)slot * ACTD + ctile + wn + rlo;
                #pragma unroll
                for (int ni = 0; ni < 4; ++ni)
                    orow[ni * 16] = f2bf(pw * (acc[mi][ni][r] + bias[wn + ni * 16 + rlo]));
            }
        }
    } else {
        float* outp = out + (size_t)which * BB * ACTD;
        #pragma unroll
        for (int mi = 0; mi < 4; ++mi) {
            #pragma unroll
            for (int r = 0; r < 4; ++r) {
                const int lrow = wm + mi * 16 + q * 4 + r;
                const int grow = idx_l[lrow];
                if (grow < 0) continue;
                const float pw = probs_l[lrow];
                float* orow = outp + (size_t)grow * ACTD + ctile + wn + rlo;
                #pragma unroll
                for (int ni = 0; ni < 4; ++ni)
                    atomicAdd(orow + ni * 16,
                              pw * (acc[mi][ni][r] + bias[wn + ni * 16 + rlo]));
            }
        }
    }
}

// -------------------------------------------------------------------------
// Combine: out[r] = sum_k partial[r*4+k]; tanh affine on lstd plane.
// One thread per (row, 4 cols). Fully coalesced.
// -------------------------------------------------------------------------
__global__ __launch_bounds__(256) void combine_kernel(
    const ushort* __restrict__ partial, float* __restrict__ out)
{
    const int t  = blockIdx.x * 256 + threadIdx.x;   // BB*64 threads
    const int r  = t >> 6;
    const int c4 = (t & 63) * 4;
    const ushort* Pm = partial;
    const ushort* Pl = partial + (size_t)BB * TK * ACTD;

    float m0 = 0.f, m1 = 0.f, m2 = 0.f, m3 = 0.f;
    float l0 = 0.f, l1 = 0.f, l2 = 0.f, l3 = 0.f;
    #pragma unroll
    for (int k = 0; k < TK; ++k) {
        const size_t off = (size_t)(r * TK + k) * ACTD + c4;
        ushort4 vm = *(const ushort4*)(Pm + off);
        ushort4 vl = *(const ushort4*)(Pl + off);
        m0 += bf2f(vm.x); m1 += bf2f(vm.y); m2 += bf2f(vm.z); m3 += bf2f(vm.w);
        l0 += bf2f(vl.x); l1 += bf2f(vl.y); l2 += bf2f(vl.z); l3 += bf2f(vl.w);
    }
    float4 mo = make_float4(m0, m1, m2, m3);
    float4 lo;
    lo.x = -5.f + 3.5f * (tanhf(l0) + 1.f);
    lo.y = -5.f + 3.5f * (tanhf(l1) + 1.f);
    lo.z = -5.f + 3.5f * (tanhf(l2) + 1.f);
    lo.w = -5.f + 3.5f * (tanhf(l3) + 1.f);
    *(float4*)(out + (size_t)r * ACTD + c4) = mo;
    *(float4*)(out + (size_t)BB * ACTD + (size_t)r * ACTD + c4) = lo;
}

// -------------------------------------------------------------------------
// Tier B: fp32 expert-grouped GEMM (round-1, proven). grid = (512, 16, 4)
// -------------------------------------------------------------------------
__global__ __launch_bounds__(256) void moe_gemm_f32(
    const float* __restrict__ x,
    const float* __restrict__ mean_w, const float* __restrict__ mean_b,
    const float* __restrict__ lstd_w, const float* __restrict__ lstd_b,
    const int* __restrict__ counts, const int* __restrict__ rowlist,
    const float* __restrict__ problist, float* __restrict__ out)
{
    const int e = blockIdx.y;
    const int cnt = counts[e];
    const int tile0 = blockIdx.x * 32;
    if (tile0 >= cnt) return;

    const int zz    = blockIdx.z;
    const int which = zz >> 1;
    const int ctile = (zz & 1) * 128;
    const float* W    = (which ? lstd_w : mean_w) + (size_t)e * ACTD * OBS;
    const float* bias = (which ? lstd_b : mean_b) + e * ACTD;
    float* outp = out + (size_t)which * BB * ACTD;

    __shared__ float xls[32][32];
    __shared__ float wls[32][128];

    const int sr  = threadIdx.x >> 3;
    const int skq = threadIdx.x & 7;
    int stage_row = -1;
    {
        const int pos = tile0 + sr;
        if (pos < cnt) stage_row = rowlist[e * BB + pos];
    }

    const int r0 = (threadIdx.x >> 5) << 2;
    const int c0 = (threadIdx.x & 31) << 2;

    float acc[4][4] = {};

    for (int kt = 0; kt < OBS; kt += 32) {
        __syncthreads();
        {
            float4 v = make_float4(0.f, 0.f, 0.f, 0.f);
            if (stage_row >= 0)
                v = *(const float4*)(x + (size_t)stage_row * OBS + kt + skq * 4);
            xls[skq * 4 + 0][sr] = v.x;
            xls[skq * 4 + 1][sr] = v.y;
            xls[skq * 4 + 2][sr] = v.z;
            xls[skq * 4 + 3][sr] = v.w;
        }
        #pragma unroll
        for (int j = 0; j < 4; ++j) {
            const int i  = threadIdx.x + 256 * j;
            const int c  = i >> 3;
            const int kq = i & 7;
            float4 v = *(const float4*)(W + (size_t)(ctile + c) * OBS + kt + kq * 4);
            wls[kq * 4 + 0][c] = v.x;
            wls[kq * 4 + 1][c] = v.y;
            wls[kq * 4 + 2][c] = v.z;
            wls[kq * 4 + 3][c] = v.w;
        }
        __syncthreads();

        #pragma unroll
        for (int k = 0; k < 32; ++k) {
            const float4 xa = *(const float4*)&xls[k][r0];
            const float4 wb = *(const float4*)&wls[k][c0];
            const float xv[4] = { xa.x, xa.y, xa.z, xa.w };
            const float wv[4] = { wb.x, wb.y, wb.z, wb.w };
            #pragma unroll
            for (int i = 0; i < 4; ++i)
                #pragma unroll
                for (int j = 0; j < 4; ++j)
                    acc[i][j] = fmaf(xv[i], wv[j], acc[i][j]);
        }
    }

    #pragma unroll
    for (int i = 0; i < 4; ++i) {
        const int pos = tile0 + r0 + i;
        if (pos >= cnt) break;
        const int grow = rowlist[e * BB + pos];
        const float pw = problist[e * BB + pos];
        float* orow = outp + (size_t)grow * ACTD + ctile + c0;
        #pragma unroll
        for (int j = 0; j < 4; ++j)
            atomicAdd(&orow[j], pw * (acc[i][j] + bias[ctile + c0 + j]));
    }
}

__global__ __launch_bounds__(256) void tanh_ep(float* __restrict__ out)
{
    const int i = blockIdx.x * 256 + threadIdx.x;
    float4* p = (float4*)(out + (size_t)BB * ACTD);
    float4 v = p[i];
    v.x = -5.f + 3.5f * (tanhf(v.x) + 1.f);
    v.y = -5.f + 3.5f * (tanhf(v.y) + 1.f);
    v.z = -5.f + 3.5f * (tanhf(v.z) + 1.f);
    v.w = -5.f + 3.5f * (tanhf(v.w) + 1.f);
    p[i] = v;
}

extern "C" void kernel_launch(void* const* d_in, const int* in_sizes, int n_in,
                              void* d_out, int out_size, void* d_ws, size_t ws_size,
                              hipStream_t stream)
{
    const float* x        = (const float*)d_in[0];
    const float* router_w = (const float*)d_in[1];
    const float* router_b = (const float*)d_in[2];
    const float* mean_w   = (const float*)d_in[3];
    const float* mean_b   = (const float*)d_in[4];
    const float* lstd_w   = (const float*)d_in[5];
    const float* lstd_b   = (const float*)d_in[6];

    float* out = (float*)d_out;
    int*    counts   = (int*)d_ws;
    int*    rowlist  = (int*)((char*)d_ws + WS_ROWLIST_OFF);
    float*  problist = (float*)((char*)d_ws + WS_PROBLIST_OFF);
    int*    slot_of  = (int*)((char*)d_ws + WS_SLOT_OFF);
    ushort* xbf      = (ushort*)((char*)d_ws + WS_XBF_OFF);
    ushort* wmbf     = (ushort*)((char*)d_ws + WS_WM_OFF);
    ushort* wlbf     = (ushort*)((char*)d_ws + WS_WL_OFF);
    ushort* partial  = (ushort*)((char*)d_ws + WS_PART_OFF);

    const bool tierA2 = (ws_size >= WS_NEEDED_A2);
    const bool tierA  = (ws_size >= WS_NEEDED_A);

    hipMemsetAsync(d_ws, 0, 64, stream);

    if (tierA) {
        const int wn4 = NE * ACTD * OBS / 4;
        cvt_bf16<<<(wn4 + 255) / 256, 256, 0, stream>>>(mean_w, wmbf, wn4);
        cvt_bf16<<<(wn4 + 255) / 256, 256, 0, stream>>>(lstd_w, wlbf, wn4);

        router_kernel<<<BB / 16, 256, 0, stream>>>(x, router_w, router_b,
                                                   counts, rowlist, problist,
                                                   slot_of, xbf, 1);

        dim3 grid(BB / 128, NE, 4);
        if (tierA2) {
            moe_gemm_mfma<<<grid, 256, 0, stream>>>(xbf, wmbf, wlbf, mean_b, lstd_b,
                                                    counts, rowlist, problist,
                                                    slot_of, partial, out, 1);
            combine_kernel<<<BB * 64 / 256, 256, 0, stream>>>(partial, out);
        } else {
            hipMemsetAsync(d_out, 0, (size_t)out_size * sizeof(float), stream);
            moe_gemm_mfma<<<grid, 256, 0, stream>>>(xbf, wmbf, wlbf, mean_b, lstd_b,
                                                    counts, rowlist, problist,
                                                    slot_of, partial, out, 0);
            tanh_ep<<<(BB * ACTD / 4) / 256, 256, 0, stream>>>(out);
        }
    } else {
        hipMemsetAsync(d_out, 0, (size_t)out_size * sizeof(float), stream);
        router_kernel<<<BB / 16, 256, 0, stream>>>(x, router_w, router_b,
                                                   counts, rowlist, problist,
                                                   (int*)nullptr, (ushort*)nullptr, 0);
        dim3 grid(BB / 32, NE, 4);
        moe_gemm_f32<<<grid, 256, 0, stream>>>(x, mean_w, mean_b, lstd_w, lstd_b,
                                               counts, rowlist, problist, out);
        tanh_ep<<<(BB * ACTD / 4) / 256, 256, 0, stream>>>(out);
    }
}